// Round 4
// baseline (229.387 us; speedup 1.0000x reference)
//
#include <hip/hip_runtime.h>

typedef __attribute__((ext_vector_type(8))) _Float16 f16x8;
typedef __attribute__((ext_vector_type(4))) float f32x4;

#define B_SZ   16
#define N_SEQ  4096
#define M_CTX  77
#define M_PAD  96
#define NH     8

__device__ __forceinline__ _Float16 f2h(float x) { return (_Float16)x; }

// async global->LDS, 16B per lane. dst = wave-uniform base; HW writes
// dst + lane*16. Source address is per-lane.
__device__ __forceinline__ void gload16(const void* g, void* l) {
    __builtin_amdgcn_global_load_lds(
        (const __attribute__((address_space(1))) unsigned int*)g,
        (__attribute__((address_space(3))) unsigned int*)l, 16, 0, 0);
}

#define BAR()   asm volatile("s_barrier" ::: "memory")
#define WAITV2() asm volatile("s_waitcnt vmcnt(2)" ::: "memory")
#define WAITV0() asm volatile("s_waitcnt vmcnt(0)" ::: "memory")

// ---- DPP 16-lane butterfly reductions (XOR masks {1,2,7,15} span 0..15) ----
template<int C>
__device__ __forceinline__ float dppf(float x) {
    union { float f; int i; } u, v;
    u.f = x;
    v.i = __builtin_amdgcn_mov_dpp(u.i, C, 0xF, 0xF, true);
    return v.f;
}
__device__ __forceinline__ float rmax16(float x) {
    x = fmaxf(x, dppf<0xB1>(x));
    x = fmaxf(x, dppf<0x4E>(x));
    x = fmaxf(x, dppf<0x141>(x));
    x = fmaxf(x, dppf<0x140>(x));
    return x;
}
__device__ __forceinline__ float rsum16(float x) {
    x += dppf<0xB1>(x);
    x += dppf<0x4E>(x);
    x += dppf<0x141>(x);
    x += dppf<0x140>(x);
    return x;
}

// ---------------------------------------------------------------------------
// convert: x fp32 -> x_h f16 (memory-bound, 201 MB traffic)
// ---------------------------------------------------------------------------
__global__ __launch_bounds__(256)
void convert(const float4* __restrict__ x, f16x8* __restrict__ xh, int n8)
{
    int idx = blockIdx.x * 256 + threadIdx.x;
    int stride = gridDim.x * 256;
    for (int i = idx; i < n8; i += stride) {
        float4 a = x[2 * i];
        float4 b = x[2 * i + 1];
        f16x8 o;
        o[0] = f2h(a.x); o[1] = f2h(a.y); o[2] = f2h(a.z); o[3] = f2h(a.w);
        o[4] = f2h(b.x); o[5] = f2h(b.y); o[6] = f2h(b.z); o[7] = f2h(b.w);
        xh[i] = o;
    }
}

// ---------------------------------------------------------------------------
// prep: W [K][512] fp32 -> WT [512][K] f16 (LDS-tiled transpose).
// Wq gets the 1/sqrt(D_HEAD)=0.125 softmax scale folded in.
// ---------------------------------------------------------------------------
__global__ __launch_bounds__(256)
void prep(const float* __restrict__ Wq, const float* __restrict__ Wk,
          const float* __restrict__ Wv, const float* __restrict__ Wo,
          _Float16* __restrict__ WqT, _Float16* __restrict__ WkT,
          _Float16* __restrict__ WvT, _Float16* __restrict__ WoT)
{
    __shared__ float t[32][33];
    const float* W; _Float16* WT; int K; float scale = 1.0f;
    switch (blockIdx.z) {
        case 0:  W = Wq; WT = WqT; K = 512; scale = 0.125f; break;
        case 1:  W = Wk; WT = WkT; K = 768; break;
        case 2:  W = Wv; WT = WvT; K = 768; break;
        default: W = Wo; WT = WoT; K = 512; break;
    }
    const int ky = blockIdx.y;
    if (ky * 32 >= K) return;
    const int nx = blockIdx.x;
    const int tr = threadIdx.x >> 5, tc = threadIdx.x & 31;
#pragma unroll
    for (int i = 0; i < 4; ++i) {
        int kr = tr + i * 8;
        t[kr][tc] = W[(size_t)(ky * 32 + kr) * 512 + nx * 32 + tc];
    }
    __syncthreads();
#pragma unroll
    for (int i = 0; i < 4; ++i) {
        int nr = tr + i * 8;
        WT[(size_t)(nx * 32 + nr) * K + ky * 32 + tc] = f2h(t[tc][nr] * scale);
    }
}

// ---------------------------------------------------------------------------
// kv_proj: writes K and V in BANK-SWIZZLED global layouts so attn can stage
// them to LDS linearly with global_load_lds and read conflict-free:
//   Kswz[bh][m][ ((d>>3)^(m&7))*8 + (d&7) ]   m in 0..95 (zeros >= 77)
//   Vswz[bh][d][ ((m>>3)^(d&7))*8 + (m&7) ]   rows of 128 f16 (slots 0..11 used)
// grid (8 h, 16 b, 2 kv); block 256 = 4 waves
// ---------------------------------------------------------------------------
__global__ __launch_bounds__(256)
void kv_proj(const float* __restrict__ cond, const _Float16* __restrict__ WkT,
             const _Float16* __restrict__ WvT, _Float16* __restrict__ Kswz,
             _Float16* __restrict__ Vswz)
{
    const int tid = threadIdx.x;
    const int l = tid & 63, w = tid >> 6;
    const int lrow = l & 15, lk = l >> 4;
    const int h = blockIdx.x, b = blockIdx.y, which = blockIdx.z;
    const _Float16* WT = which ? WvT : WkT;
    const float* cb = cond + (size_t)b * M_CTX * 768;

    f32x4 acc[5];
#pragma unroll
    for (int i = 0; i < 5; ++i)
#pragma unroll
        for (int e = 0; e < 4; ++e) acc[i][e] = 0.f;

    const int n = h * 64 + w * 16 + lrow;
    for (int kk = 0; kk < 24; ++kk) {
        f16x8 bfrag = *(const f16x8*)(WT + (size_t)n * 768 + kk * 32 + lk * 8);
#pragma unroll
        for (int rt = 0; rt < 5; ++rt) {
            int m = rt * 16 + lrow;
            f16x8 afrag;
#pragma unroll
            for (int j = 0; j < 8; ++j) afrag[j] = (_Float16)0.f;
            if (m < M_CTX) {
                const float* a = cb + (size_t)m * 768 + kk * 32 + lk * 8;
                float4 f0 = *(const float4*)a;
                float4 f1 = *(const float4*)(a + 4);
                afrag[0] = f2h(f0.x); afrag[1] = f2h(f0.y);
                afrag[2] = f2h(f0.z); afrag[3] = f2h(f0.w);
                afrag[4] = f2h(f1.x); afrag[5] = f2h(f1.y);
                afrag[6] = f2h(f1.z); afrag[7] = f2h(f1.w);
            }
            acc[rt] = __builtin_amdgcn_mfma_f32_16x16x32_f16(afrag, bfrag, acc[rt], 0, 0, 0);
        }
    }

    const int bh = b * NH + h;
    const int d = w * 16 + lrow;
    const int dhi = d >> 3, dlo = d & 7;
    if (which == 0) {
        _Float16* Kb = Kswz + (size_t)bh * (M_PAD * 64);
#pragma unroll
        for (int rt = 0; rt < 5; ++rt)
#pragma unroll
            for (int r = 0; r < 4; ++r) {
                int m = rt * 16 + lk * 4 + r;
                Kb[m * 64 + ((dhi ^ (m & 7)) * 8) + dlo] = f2h(acc[rt][r]);
            }
#pragma unroll
        for (int r = 0; r < 4; ++r) {
            int m = 80 + lk * 4 + r;
            Kb[m * 64 + ((dhi ^ (m & 7)) * 8) + dlo] = (_Float16)0.f;
        }
    } else {
        _Float16* Vb = Vswz + (size_t)bh * (64 * 128);
#pragma unroll
        for (int rt = 0; rt < 5; ++rt)
#pragma unroll
            for (int r = 0; r < 4; ++r) {
                int m = rt * 16 + lk * 4 + r;
                Vb[d * 128 + (((m >> 3) ^ dlo) * 8) + (m & 7)] = f2h(acc[rt][r]);
            }
#pragma unroll
        for (int r = 0; r < 4; ++r) {
            int m = 80 + lk * 4 + r;
            Vb[d * 128 + (((m >> 3) ^ dlo) * 8) + (m & 7)] = (_Float16)0.f;
        }
    }
}

// ---------------------------------------------------------------------------
// gemm256: C[65536][512] = A[65536][512] @ B (BT[512][512] f16).
// 8-phase-style pipelined template: BM=BN=256, BK=32, 8 waves (2Mx4N),
// 64KB LDS double-buffer, counted vmcnt(2) (never 0 in main loop),
// setprio around MFMA clusters, raw s_barrier. BK=32 => fragment K-slot = lk,
// waves read full 16-row LDS spans => bank-conflict-free without swizzle.
// Schedule per K-tile t (buf bt = t&1):
//   q0: read af0-3,bf0-3(t); stage A(t+1)->buf bt^1; BAR; 16 MFMA
//   q1: read af4-7(t); stage B(t+2)->buf bt; 16 MFMA; vmcnt(2); BAR
// WAR: A(buf) last read q1 (stage next iter q0, after BAR); B(buf) last read
// q0 (stage q1, after mid BAR). RAW: vmcnt(2) leaves only B(t+2) in flight.
// EMODE 0: C f16; EMODE 1: C fp32 + bias.
// ---------------------------------------------------------------------------
template<int EMODE>
__global__ __launch_bounds__(512, 2)
void gemm256(const _Float16* __restrict__ A, const _Float16* __restrict__ BT,
             void* __restrict__ Cv, const float* __restrict__ bias)
{
    __shared__ _Float16 As[32768];   // [buf][half][128 rows][32] f16 = 32KB
    __shared__ _Float16 Bs[32768];

    // XCD-chunked bijective swizzle: 512 = 8 * 64
    const int bid = blockIdx.x;
    const int wg = (bid & 7) * 64 + (bid >> 3);
    const int rb = wg >> 1, cb = wg & 1;
    const size_t row0 = (size_t)rb * 256;
    const int col0 = cb * 256;

    const int tid = threadIdx.x;
    const int l = tid & 63, w = tid >> 6;
    const int wy = w >> 2, wx = w & 3;           // 2M x 4N wave grid
    const int lrow = l & 15, lk = l >> 4;

    f32x4 acc[8][4];
#pragma unroll
    for (int i = 0; i < 8; ++i)
#pragma unroll
        for (int j = 0; j < 4; ++j)
#pragma unroll
            for (int e = 0; e < 4; ++e) acc[i][j][e] = 0.f;

    // staging: thread covers row tid>>2 (of 128), 16B slot tid&3; linear LDS.
    const _Float16* a_src = A + (row0 + (size_t)(tid >> 2)) * 512 + (tid & 3) * 8;
    const _Float16* b_src = BT + (size_t)(col0 + (tid >> 2)) * 512 + (tid & 3) * 8;
    _Float16* As_d = &As[w * 512];               // + buf*8192 + half*4096
    _Float16* Bs_d = &Bs[w * 512];

    auto stageA = [&](int t) {
        const _Float16* s = a_src + t * 32;
        _Float16* d = As_d + (t & 1) * 8192;
        gload16(s, d);                            // half 0 (rows 0..127)
        gload16(s + 128 * 512, d + 4096);         // half 1 (rows 128..255)
    };
    auto stageB = [&](int t) {
        const _Float16* s = b_src + t * 32;
        _Float16* d = Bs_d + (t & 1) * 8192;
        gload16(s, d);
        gload16(s + 128 * 512, d + 4096);
    };

    // prologue: tile 0 fully + B(1); vmcnt(2) -> tile 0 resident, B(1) flying
    stageA(0); stageB(0); stageB(1);
    WAITV2();
    BAR();

    // ds_read bases: A half = wy; B half = wx>>1, row (wx&1)*64 + nt*16 + lrow
    const _Float16* Ar = &As[wy * 4096 + lrow * 32 + lk * 8];
    const _Float16* Br = &Bs[(wx >> 1) * 4096 + ((wx & 1) * 64 + lrow) * 32 + lk * 8];

    for (int t = 0; t < 16; ++t) {
        const int bo = (t & 1) * 8192;
        f16x8 af[4], bf[4];
#pragma unroll
        for (int i = 0; i < 4; ++i) af[i] = *(const f16x8*)(Ar + bo + i * 512);
#pragma unroll
        for (int i = 0; i < 4; ++i) bf[i] = *(const f16x8*)(Br + bo + i * 512);
        if (t + 1 < 16) stageA(t + 1);
        BAR();
        __builtin_amdgcn_s_setprio(1);
#pragma unroll
        for (int mt = 0; mt < 4; ++mt)
#pragma unroll
            for (int nt = 0; nt < 4; ++nt)
                acc[mt][nt] = __builtin_amdgcn_mfma_f32_16x16x32_f16(af[mt], bf[nt], acc[mt][nt], 0, 0, 0);
        __builtin_amdgcn_s_setprio(0);

        f16x8 ag[4];
#pragma unroll
        for (int i = 0; i < 4; ++i) ag[i] = *(const f16x8*)(Ar + bo + (4 + i) * 512);
        if (t + 2 < 16) stageB(t + 2);
        __builtin_amdgcn_s_setprio(1);
#pragma unroll
        for (int mt = 0; mt < 4; ++mt)
#pragma unroll
            for (int nt = 0; nt < 4; ++nt)
                acc[4 + mt][nt] = __builtin_amdgcn_mfma_f32_16x16x32_f16(ag[mt], bf[nt], acc[4 + mt][nt], 0, 0, 0);
        __builtin_amdgcn_s_setprio(0);

        if (t <= 13)      WAITV2();   // A(t+1),B(t+1) landed; B(t+2) flying
        else if (t == 14) WAITV0();   // tail: everything must land
        if (t < 15) BAR();
    }

    // epilogue
#pragma unroll
    for (int mt = 0; mt < 8; ++mt)
#pragma unroll
        for (int nt = 0; nt < 4; ++nt)
#pragma unroll
            for (int r = 0; r < 4; ++r) {
                size_t row = row0 + wy * 128 + mt * 16 + lk * 4 + r;
                int col = col0 + wx * 64 + nt * 16 + lrow;
                float v = acc[mt][nt][r];
                if (EMODE == 0) {
                    ((_Float16*)Cv)[row * 512 + col] = f2h(v);
                } else {
                    ((float*)Cv)[row * 512 + col] = v + bias[col];
                }
            }
}

// ---------------------------------------------------------------------------
// attn: one block = one (b,h) x 256 Q-rows. K,V staged to LDS once (swizzled
// layouts pre-baked in global). 4 waves x 64 rows. DPP softmax reductions,
// deferred 1/sum normalization into the O epilogue.
// grid (16 chunks, 8 h, 16 b); block 256.
// ---------------------------------------------------------------------------
__global__ __launch_bounds__(256)
void attn(const _Float16* __restrict__ Q, const _Float16* __restrict__ Kswz,
          const _Float16* __restrict__ Vswz, _Float16* __restrict__ AO)
{
    __shared__ _Float16 Ks[M_PAD * 64];    // 12KB: row m, slot s at s^(m&7)
    __shared__ _Float16 Vs[64 * 128];      // 16KB: row d, slot s at s^(d&7)
    __shared__ _Float16 Pl[4][16][104];    // 13KB: per-wave P tile

    const int tid = threadIdx.x;
    const int l = tid & 63, w = tid >> 6;
    const int lrow = l & 15, lk = l >> 4;
    const int chunk = blockIdx.x, h = blockIdx.y, b = blockIdx.z;
    const int bh = b * NH + h;

    {
        const _Float16* Kg = Kswz + (size_t)bh * (M_PAD * 64);
        const _Float16* Vg = Vswz + (size_t)bh * (64 * 128);
#pragma unroll
        for (int i = 0; i < 3; ++i) {
            int c = w * 3 + i;
            gload16(Kg + c * 512 + l * 8, Ks + c * 512);
        }
#pragma unroll
        for (int i = 0; i < 4; ++i) {
            int c = w * 4 + i;
            gload16(Vg + c * 512 + l * 8, Vs + c * 512);
        }
    }

    const size_t row0 = (size_t)b * N_SEQ + chunk * 256 + w * 64;
    f16x8 af[4][2];
    {
        const _Float16* Qb = Q + (row0 + lrow) * 512 + h * 64 + lk * 8;
#pragma unroll
        for (int mt = 0; mt < 4; ++mt)
#pragma unroll
            for (int kk = 0; kk < 2; ++kk)
                af[mt][kk] = *(const f16x8*)(Qb + (size_t)mt * 16 * 512 + kk * 32);
    }

    for (int idx = l; idx < 256; idx += 64)
        Pl[w][idx >> 4][80 + (idx & 15)] = (_Float16)0.f;

    __syncthreads();   // drains vmcnt: K/V in LDS

    const bool m4ok = (lrow < 13);
    const int kswz = lrow & 7;

#pragma unroll
    for (int mt = 0; mt < 4; ++mt) {
        f32x4 s[5];
#pragma unroll
        for (int i = 0; i < 5; ++i)
#pragma unroll
            for (int e = 0; e < 4; ++e) s[i][e] = 0.f;
#pragma unroll
        for (int kk = 0; kk < 2; ++kk)
#pragma unroll
            for (int ct = 0; ct < 5; ++ct) {
                f16x8 kf = *(const f16x8*)&Ks[(ct * 16 + lrow) * 64 + (((kk * 4 + lk) ^ kswz) * 8)];
                s[ct] = __builtin_amdgcn_mfma_f32_16x16x32_f16(af[mt][kk], kf, s[ct], 0, 0, 0);
            }

        float rinv[4];
#pragma unroll
        for (int r = 0; r < 4; ++r) {
            float v0 = s[0][r], v1 = s[1][r], v2 = s[2][r], v3 = s[3][r], v4 = s[4][r];
            float mx = fmaxf(fmaxf(v0, v1), fmaxf(v2, v3));
            mx = fmaxf(mx, m4ok ? v4 : -1e30f);
            mx = rmax16(mx);
            float e0 = __expf(v0 - mx), e1 = __expf(v1 - mx);
            float e2 = __expf(v2 - mx), e3 = __expf(v3 - mx);
            float e4 = m4ok ? __expf(v4 - mx) : 0.f;
            float sum = ((e0 + e1) + (e2 + e3)) + e4;
            sum = rsum16(sum);
            rinv[r] = 1.0f / sum;
            int prow = lk * 4 + r;
            Pl[w][prow][lrow]      = f2h(e0);
            Pl[w][prow][16 + lrow] = f2h(e1);
            Pl[w][prow][32 + lrow] = f2h(e2);
            Pl[w][prow][48 + lrow] = f2h(e3);
            Pl[w][prow][64 + lrow] = f2h(e4);
        }

        f32x4 o[4];
#pragma unroll
        for (int i = 0; i < 4; ++i)
#pragma unroll
            for (int e2 = 0; e2 < 4; ++e2) o[i][e2] = 0.f;
#pragma unroll
        for (int kk = 0; kk < 3; ++kk) {
            f16x8 pa = *(const f16x8*)&Pl[w][lrow][kk * 32 + lk * 8];
#pragma unroll
            for (int ctd = 0; ctd < 4; ++ctd) {
                f16x8 vf = *(const f16x8*)&Vs[(ctd * 16 + lrow) * 128 + (((kk * 4 + lk) ^ kswz) * 8)];
                o[ctd] = __builtin_amdgcn_mfma_f32_16x16x32_f16(pa, vf, o[ctd], 0, 0, 0);
            }
        }

        const size_t rw = row0 + mt * 16 + lk * 4;
#pragma unroll
        for (int ctd = 0; ctd < 4; ++ctd)
#pragma unroll
            for (int r = 0; r < 4; ++r)
                AO[(rw + r) * 512 + h * 64 + ctd * 16 + lrow] = f2h(o[ctd][r] * rinv[r]);
    }
}

// ---------------------------------------------------------------------------
extern "C" void kernel_launch(void* const* d_in, const int* in_sizes, int n_in,
                              void* d_out, int out_size, void* d_ws, size_t ws_size,
                              hipStream_t stream)
{
    (void)in_sizes; (void)n_in; (void)out_size; (void)ws_size;
    const float* x    = (const float*)d_in[0];
    const float* cond = (const float*)d_in[1];
    const float* Wq   = (const float*)d_in[2];
    const float* Wk   = (const float*)d_in[3];
    const float* Wv   = (const float*)d_in[4];
    const float* Wo   = (const float*)d_in[5];
    const float* bo   = (const float*)d_in[6];

    char* ws = (char*)d_ws;
    _Float16* WqT  = (_Float16*)(ws);                        // 524288
    _Float16* WoT  = (_Float16*)(ws + 524288);               // 524288
    _Float16* Kswz = (_Float16*)(ws + 1048576);              // 1572864
    _Float16* Vswz = (_Float16*)(ws + 2621440);              // 2097152
    _Float16* xh   = (_Float16*)(ws + 4718592);              // 67108864
    _Float16* WkT  = (_Float16*)(ws + 4718592);              // aliases xh head
    _Float16* WvT  = (_Float16*)(ws + 4718592 + 786432);     // (dead pre-convert)
    _Float16* AO   = xh;                                     // xh dead after gemm<0>
    _Float16* Qf   = (_Float16*)d_out;                       // dead before gemm<1>

    prep<<<dim3(16, 24, 4), 256, 0, stream>>>(Wq, Wk, Wv, Wo, WqT, WkT, WvT, WoT);
    kv_proj<<<dim3(8, 16, 2), 256, 0, stream>>>(cond, WkT, WvT, Kswz, Vswz);
    convert<<<dim3(2048), 256, 0, stream>>>((const float4*)x, (f16x8*)xh, 16 * 4096 * 512 / 8);
    gemm256<0><<<dim3(512), 512, 0, stream>>>(xh, WqT, Qf, nullptr);
    attn<<<dim3(16, 8, 16), 256, 0, stream>>>(Qf, Kswz, Vswz, AO);
    gemm256<1><<<dim3(512), 512, 0, stream>>>(AO, WoT, d_out, bo);
}